// Round 8
// baseline (564.807 us; speedup 1.0000x reference)
//
#include <hip/hip_runtime.h>
#include <math.h>

#define B_    128
#define L_    64
#define C_    300
#define NH_   300
#define K_    20
#define HID_  150
#define N_    (B_*L_)       // 8192
#define N2_   (2*N_)        // 16384
#define NFEAT_ 44427
#define ZSPLIT_ 512
#define KCHUNK_ 87          // 512*87 = 44544 >= 44427
#define CP_   320           // padded C for bf16 GEMM (mult of 32)
#define NROWS_ 16448        // 257*64: N2_ + pad rows (staging window reads up to +79)

typedef __attribute__((ext_vector_type(8))) short bf16x8;
typedef __attribute__((ext_vector_type(4))) float f32x4;

__device__ __forceinline__ float fast_tanh(float x){
    float e = __expf(2.0f*x);
    return 1.0f - 2.0f/(e + 1.0f);
}

__device__ __forceinline__ unsigned short f2bf(float x){
    union { float f; unsigned u; } a; a.f = x;
    unsigned r = a.u + 0x7FFFu + ((a.u >> 16) & 1u);   // RNE
    return (unsigned short)(r >> 16);
}

// ---------------------------------------------------------------- embedding
// S[c, s*N + b*64 + l] = emb[tok(s,b,l), c]   (fp32, for pdim/inf kernels)
__global__ void k_embed(const int* __restrict__ sa, const int* __restrict__ sb,
                        const float* __restrict__ emb, float* __restrict__ S){
    int n = blockIdx.x*256 + threadIdx.x;      // 0..16383
    int s = n >> 13;
    int nl = n & (N_-1);
    int tok = s ? sb[nl] : sa[nl];
    const float* row = emb + (long)tok * C_;
    for (int c = 0; c < C_; ++c)
        S[(long)c*N2_ + n] = row[c];
}

// ------------------------------------------------- transposed bf16 S: SbfT[n][c]
__global__ void k_embedT(const int* __restrict__ sa, const int* __restrict__ sb,
                         const float* __restrict__ emb, unsigned short* __restrict__ sbfT){
    int w = threadIdx.x >> 6, lane = threadIdx.x & 63;
    for (int i = 0; i < 16; ++i){
        long n = (long)blockIdx.x*64 + w*16 + i;
        if (n >= NROWS_) return;
        bool pad = (n >= N2_);
        int tok = 0;
        if (!pad) tok = (n >= N_) ? sb[n - N_] : sa[n];
        const float4* er = (const float4*)(emb + (long)tok * C_);
        #pragma unroll
        for (int p = 0; p < 2; ++p){
            int c4 = p*64 + lane;            // float4 index, c = 4*c4
            if (c4 >= CP_/4) continue;
            ushort4 v = {0,0,0,0};
            if (!pad && c4 < 75){
                float4 f = er[c4];
                v.x = f2bf(f.x); v.y = f2bf(f.y); v.z = f2bf(f.z); v.w = f2bf(f.w);
            }
            ((ushort4*)(sbfT + n*CP_))[c4] = v;
        }
    }
}

// ------------------------------------------------- bf16 conv weights, [plane][o][c]
__global__ void k_wprep(const float* __restrict__ hw1, const float* __restrict__ hw2,
                        const float* __restrict__ hw3, unsigned short* __restrict__ wbf){
    int idx = blockIdx.x*256 + threadIdx.x;    // < 6*320*320 = 614400
    int p = idx / (CP_*CP_), r = idx % (CP_*CP_);
    int o = r / CP_, c = r % CP_;
    int WS, j; const float* hw;
    if (p == 0){ WS = 1; j = 0; hw = hw1; }
    else if (p < 3){ WS = 2; j = p - 1; hw = hw2; }
    else { WS = 3; j = p - 3; hw = hw3; }
    float v = (o < NH_ && c < C_) ? hw[((long)o*C_ + c)*WS + j] : 0.0f;
    wbf[idx] = f2bf(v);
}

// ------------------------------------------------- holistic conv via MFMA, LDS-staged
// Per kc chunk (32 c): block stages A (80 rows x 32c) + B (160o x 32c x WS) into LDS
// through registers; barrier forces loads for kc+1 to stay in flight across the
// MFMA phase (compiler can't sink them past the barrier - fixes R5/R7 serialization).
// LDS entries are 16B units: A[qc][row], B[j][qc][o] -> all ds_read_b128 2-way (free).
template<int WS>
__global__ __launch_bounds__(256) void k_hconv3(const unsigned short* __restrict__ sbfT,
        const unsigned short* __restrict__ wbf, const float* __restrict__ hb,
        float* __restrict__ apool){
    const int Lo = 65 - WS;
    const int NB = 160*4*WS;                 // B 16B-entries per chunk
    const int NBIT = (NB + 255)/256;
    __shared__ float4 AL[320];               // [qc][80 rows]
    __shared__ float4 BL[160*4*WS];          // [j][qc][160 o]
    __shared__ float P[5][160][3];
    int tid = threadIdx.x;
    int w = tid >> 6, lane = tid & 63, col = lane & 15, quad = lane >> 4;
    int sbx = blockIdx.x, nhalf = blockIdx.y;
    int s = sbx >> 7, b = sbx & 127;
    long row0 = (long)sbx*64;
    int mt0 = (w>>1)*2;                      // wave's first m-tile
    int olocb = (w&1)*80 + col;              // + ni*16
    int nbase = nhalf*160;

    float4 ga[2], gb[NBIT];
    f32x4 acc[2][5] = {};

    // prologue: global-load chunk 0 into registers
    #pragma unroll
    for (int i = 0; i < 2; ++i){
        int e = tid + i*256;
        if (e < 320){
            int qc = e / 80, rr = e % 80;
            ga[i] = *(const float4*)(sbfT + (row0 + rr)*CP_ + qc*8);
        }
    }
    #pragma unroll
    for (int i = 0; i < NBIT; ++i){
        int e = tid + i*256;
        if (e < NB){
            int j = e / 640, r2 = e % 640;
            int qc = r2 / 160, o = r2 % 160;
            gb[i] = *(const float4*)(wbf + (long)j*CP_*CP_ + (long)(nbase+o)*CP_ + qc*8);
        }
    }

    for (int kc = 0; kc < 10; ++kc){
        __syncthreads();                     // prior chunk's ds_reads done
        #pragma unroll
        for (int i = 0; i < 2; ++i){
            int e = tid + i*256;
            if (e < 320) AL[e] = ga[i];
        }
        #pragma unroll
        for (int i = 0; i < NBIT; ++i){
            int e = tid + i*256;
            if (e < NB) BL[e] = gb[i];
        }
        __syncthreads();
        if (kc < 9){
            int k0 = (kc+1)*32;
            #pragma unroll
            for (int i = 0; i < 2; ++i){
                int e = tid + i*256;
                if (e < 320){
                    int qc = e / 80, rr = e % 80;
                    ga[i] = *(const float4*)(sbfT + (row0 + rr)*CP_ + k0 + qc*8);
                }
            }
            #pragma unroll
            for (int i = 0; i < NBIT; ++i){
                int e = tid + i*256;
                if (e < NB){
                    int j = e / 640, r2 = e % 640;
                    int qc = r2 / 160, o = r2 % 160;
                    gb[i] = *(const float4*)(wbf + (long)j*CP_*CP_ + (long)(nbase+o)*CP_ + k0 + qc*8);
                }
            }
        }
        #pragma unroll
        for (int j = 0; j < WS; ++j){
            bf16x8 a0 = *(const bf16x8*)&AL[quad*80 + mt0*16 + col + j];
            bf16x8 a1 = *(const bf16x8*)&AL[quad*80 + (mt0+1)*16 + col + j];
            #pragma unroll
            for (int ni = 0; ni < 5; ++ni){
                bf16x8 bfr = *(const bf16x8*)&BL[(j*4+quad)*160 + olocb + ni*16];
                acc[0][ni] = __builtin_amdgcn_mfma_f32_16x16x32_bf16(a0, bfr, acc[0][ni], 0,0,0);
                acc[1][ni] = __builtin_amdgcn_mfma_f32_16x16x32_bf16(a1, bfr, acc[1][ni], 0,0,0);
            }
        }
    }

    float rmax[5], rmin[5], rsum[5];
    #pragma unroll
    for (int ni = 0; ni < 5; ++ni){
        int oloc = olocb + ni*16;
        int o = nbase + oloc;
        float bias = (o < NH_) ? hb[o] : 0.0f;
        float vmax = -1e30f, vmin = 1e30f, vsum = 0.0f;
        #pragma unroll
        for (int mi = 0; mi < 2; ++mi){
            int mt = mt0 + mi;
            #pragma unroll
            for (int r = 0; r < 4; ++r){
                int t = mt*16 + quad*4 + r;
                if (t < Lo){
                    float z = acc[mi][ni][r] + bias;
                    vmax = fmaxf(vmax, z); vmin = fminf(vmin, z);
                    vsum += fast_tanh(z);
                }
            }
        }
        for (int m = 16; m < 64; m <<= 1){
            vmax = fmaxf(vmax, __shfl_xor(vmax, m, 64));
            vmin = fminf(vmin, __shfl_xor(vmin, m, 64));
            vsum += __shfl_xor(vsum, m, 64);
        }
        rmax[ni] = vmax; rmin[ni] = vmin; rsum[ni] = vsum;
        if (w < 2 && quad == 0){
            P[ni][oloc][0] = vmax; P[ni][oloc][1] = vmin; P[ni][oloc][2] = vsum;
        }
    }
    __syncthreads();
    if (w >= 2 && quad == 0){
        #pragma unroll
        for (int ni = 0; ni < 5; ++ni){
            int oloc = olocb + ni*16;
            int o = nbase + oloc;
            if (o < NH_){
                float vmax = fmaxf(rmax[ni], P[ni][oloc][0]);
                float vmin = fminf(rmin[ni], P[ni][oloc][1]);
                float vsum = rsum[ni] + P[ni][oloc][2];
                long base = ((long)((s*3 + (WS-1))*3)) * (long)(B_*NH_) + (long)b*NH_ + o;
                apool[base]                  = fast_tanh(vmax);
                apool[base + (long)(B_*NH_)] = -fast_tanh(vmin);
                apool[base + 2L*(B_*NH_)]    = vsum / (float)Lo;
            }
        }
    }
}

// ------------------------------------------------- per-dim conv + pooling v2
__global__ __launch_bounds__(256) void k_pdim(const float* __restrict__ S,
    const float* __restrict__ pw1, const float* __restrict__ pb1,
    const float* __restrict__ pw2, const float* __restrict__ pb2,
    const float* __restrict__ pw3, const float* __restrict__ pb3,
    float* __restrict__ ppool){
    long tid = (long)blockIdx.x*256 + threadIdx.x;   // < 1,536,000
    int k = (int)(tid % 20);
    long r = tid / 20;
    int c = (int)(r % 300); r /= 300;
    int b = (int)(r % 128); int s = (int)(r / 128);
    const float* row = S + (long)c*N2_ + (long)s*N_ + b*64;
    int ck = c*20 + k;
    float w10 = pw1[ck];
    float w20 = pw2[ck*2], w21 = pw2[ck*2+1];
    float w30 = pw3[ck*3], w31 = pw3[ck*3+1], w32 = pw3[ck*3+2];
    float bb1 = pb1[ck], bb2 = pb2[ck], bb3 = pb3[ck];

    float x[64];
    const float4* rp = (const float4*)row;
    #pragma unroll
    for (int i = 0; i < 16; ++i){
        float4 v = rp[i];
        x[i*4+0]=v.x; x[i*4+1]=v.y; x[i*4+2]=v.z; x[i*4+3]=v.w;
    }

    float mx1=-1e30f, mn1=1e30f, mx2=-1e30f, mn2=1e30f, mx3=-1e30f, mn3=1e30f;
    #pragma unroll
    for (int t = 0; t < 64; ++t){
        float z1 = fmaf(w10, x[t], bb1);
        mx1 = fmaxf(mx1, z1); mn1 = fminf(mn1, z1);
    }
    #pragma unroll
    for (int t = 0; t < 63; ++t){
        float z2 = fmaf(w21, x[t+1], fmaf(w20, x[t], bb2));
        mx2 = fmaxf(mx2, z2); mn2 = fminf(mn2, z2);
    }
    #pragma unroll
    for (int t = 0; t < 62; ++t){
        float z3 = fmaf(w32, x[t+2], fmaf(w31, x[t+1], fmaf(w30, x[t], bb3)));
        mx3 = fmaxf(mx3, z3); mn3 = fminf(mn3, z3);
    }

    float outs[6] = { fast_tanh(mx1), -fast_tanh(mn1),
                      fast_tanh(mx2), -fast_tanh(mn2),
                      fast_tanh(mx3), -fast_tanh(mn3) };
    long stride_sw = 128L*6000L;
    long off = (long)b*6000 + (long)c*20 + k;
    #pragma unroll
    for (int wsi = 0; wsi < 3; ++wsi)
        #pragma unroll
        for (int pool = 0; pool < 2; ++pool){
            long slot = (long)((s*3+wsi)*2 + pool);
            ppool[slot*stride_sw + off] = outs[wsi*2+pool];
        }
}

// ------------------------------------------------- whole-sentence (inf) pools
__global__ void k_inf(const float* __restrict__ S, float* __restrict__ ainf){
    int sbx = blockIdx.x; int s = sbx >> 7, b = sbx & 127;
    int tid = threadIdx.x;
    long base = (long)s*N_ + b*64;
    float vmax = -1e30f, vnmax = -1e30f, vsum = 0.f;
    for (int idx = tid; idx < C_*64; idx += 256){
        int c = idx >> 6, l = idx & 63;
        float v = S[(long)c*N2_ + base + l];
        vmax = fmaxf(vmax, v);
        vnmax = fmaxf(vnmax, -v);
        vsum += v;
    }
    for (int m = 1; m < 64; m <<= 1){
        vmax  = fmaxf(vmax,  __shfl_xor(vmax, m, 64));
        vnmax = fmaxf(vnmax, __shfl_xor(vnmax, m, 64));
        vsum += __shfl_xor(vsum, m, 64);
    }
    __shared__ float red[3][4];
    int w = tid >> 6;
    if ((tid & 63) == 0){ red[0][w]=vmax; red[1][w]=vnmax; red[2][w]=vsum; }
    __syncthreads();
    if (tid == 0){
        float a = fmaxf(fmaxf(red[0][0],red[0][1]),fmaxf(red[0][2],red[0][3]));
        float nn= fmaxf(fmaxf(red[1][0],red[1][1]),fmaxf(red[1][2],red[1][3]));
        float su= red[2][0]+red[2][1]+red[2][2]+red[2][3];
        ainf[(s*3+0)*128 + b] = a;
        ainf[(s*3+1)*128 + b] = nn;
        ainf[(s*3+2)*128 + b] = su / (float)(C_*64);
    }
}

// ------------------------------------------------- finite-ws pair features
__global__ void k_pairs(const float* __restrict__ apool, float* __restrict__ feat){
    int b = blockIdx.x, p = blockIdx.y, q = blockIdx.z;
    int w1 = q / 3, w2 = q % 3;
    int lane = threadIdx.x;
    const float* x1 = apool + ((long)((0*3 + w1)*3 + p))*(long)(B_*NH_) + (long)b*NH_;
    const float* x2 = apool + ((long)((1*3 + w2)*3 + p))*(long)(B_*NH_) + (long)b*NH_;
    float dot=0, n1=0, n2=0, d2=0;
    long fb = (long)b*NFEAT_;
    long vbase = 24 + (long)p*2721 + (long)q*302;
    for (int i = lane; i < NH_; i += 64){
        float a = x1[i], bb = x2[i];
        dot = fmaf(a, bb, dot); n1 = fmaf(a, a, n1); n2 = fmaf(bb, bb, n2);
        float dd = a - bb + 1e-6f;
        d2 = fmaf(dd, dd, d2);
        feat[fb + vbase + 2 + i] = fabsf(a - bb);
    }
    for (int m = 1; m < 64; m <<= 1){
        dot += __shfl_xor(dot, m, 64);
        n1  += __shfl_xor(n1, m, 64);
        n2  += __shfl_xor(n2, m, 64);
        d2  += __shfl_xor(d2, m, 64);
    }
    if (lane == 0){
        float cosv = dot / fmaxf(sqrtf(n1)*sqrtf(n2), 1e-8f);
        float distv = sqrtf(d2);
        feat[fb + vbase + 0] = cosv;
        feat[fb + vbase + 1] = distv;
        if (w1 == w2){
            feat[fb + p*8 + w1*2 + 0] = cosv;
            feat[fb + p*8 + w1*2 + 1] = distv;
        }
    }
}

// ------------------------------------------------- inf features (scalar dims)
__global__ void k_infeat(const float* __restrict__ ainf, float* __restrict__ feat){
    int t = threadIdx.x;
    if (t >= 384) return;
    int b = t & 127, p = t >> 7;
    float x1 = ainf[(0*3+p)*128 + b];
    float x2 = ainf[(1*3+p)*128 + b];
    float cosv = (x1*x2) / fmaxf(fabsf(x1)*fabsf(x2), 1e-8f);
    float distv = fabsf(x1 - x2 + 1e-6f);
    long fb = (long)b*NFEAT_;
    feat[fb + p*8 + 6] = cosv;
    feat[fb + p*8 + 7] = distv;
    long vb = 24 + (long)p*2721 + 9L*302;
    feat[fb + vb + 0] = cosv;
    feat[fb + vb + 1] = distv;
    feat[fb + vb + 2] = fabsf(x1 - x2);
}

// ------------------------------------------------- per-dim pair features
__global__ void k_pdimfeat(const float* __restrict__ ppool, float* __restrict__ feat){
    int b = blockIdx.x, pw = blockIdx.y, k = blockIdx.z;
    int pool = pw / 3, wsi = pw % 3;
    int lane = threadIdx.x;
    long stride_sw = 128L*6000L;
    long off = (long)b*6000 + k;
    const float* x1 = ppool + (long)((0*3+wsi)*2+pool)*stride_sw + off;
    const float* x2 = ppool + (long)((1*3+wsi)*2+pool)*stride_sw + off;
    float dot=0, n1=0, n2=0, d2=0;
    long fb = (long)b*NFEAT_ + 8187 + (long)pw*6040 + (long)k*302;
    for (int c = lane; c < C_; c += 64){
        float a = x1[(long)c*20], bb = x2[(long)c*20];
        dot = fmaf(a, bb, dot); n1 = fmaf(a, a, n1); n2 = fmaf(bb, bb, n2);
        float dd = a - bb + 1e-6f;
        d2 = fmaf(dd, dd, d2);
        feat[fb + 2 + c] = fabsf(a - bb);
    }
    for (int m = 1; m < 64; m <<= 1){
        dot += __shfl_xor(dot, m, 64);
        n1  += __shfl_xor(n1, m, 64);
        n2  += __shfl_xor(n2, m, 64);
        d2  += __shfl_xor(d2, m, 64);
    }
    if (lane == 0){
        feat[fb + 0] = dot / fmaxf(sqrtf(n1)*sqrtf(n2), 1e-8f);
        feat[fb + 1] = sqrtf(d2);
    }
}

// ------------------------------------------------- MLP layer 1: split-K GEMM v4
__global__ __launch_bounds__(512) void k_mlp1(const float* __restrict__ feat,
        const float* __restrict__ W1, float* __restrict__ hpart){
    __shared__ __align__(16) float AlT[32][132];   // [kx][m], reads broadcast
    __shared__ __align__(16) float Bl[32][164];    // [kx][n], pad 160->164
    int tid = threadIdx.x;
    int mt = tid >> 5;            // 0..15 -> m-base mt*8
    int nt = tid & 31;            // n = nt + 32*j
    int z  = blockIdx.x;
    int k0 = z * KCHUNK_;
    int kend = min(k0 + KCHUNK_, NFEAT_);
    float acc[8][5] = {};
    for (int kk = k0; kk < kend; kk += 32){
        {
            int kx = tid & 31, mb = tid >> 5;     // mb 0..15
            int kg = kk + kx;
            #pragma unroll
            for (int i = 0; i < 8; ++i){
                int m = mb + i*16;
                AlT[kx][m] = (kg < kend) ? feat[(long)m*NFEAT_ + kg] : 0.0f;
            }
        }
        #pragma unroll
        for (int i = 0; i < 10; ++i){
            int idx = tid + i*512;        // 0..5119
            int j = idx % 160, r = idx / 160;
            int kg = kk + r;
            Bl[r][j] = (kg < kend && j < HID_) ? W1[(long)kg*HID_ + j] : 0.0f;
        }
        __syncthreads();
        #pragma unroll 4
        for (int kx = 0; kx < 32; ++kx){
            float4 a0 = *(const float4*)&AlT[kx][mt*8];
            float4 a1 = *(const float4*)&AlT[kx][mt*8+4];
            float av[8] = {a0.x,a0.y,a0.z,a0.w, a1.x,a1.y,a1.z,a1.w};
            float bv[5];
            #pragma unroll
            for (int j = 0; j < 5; ++j) bv[j] = Bl[kx][nt + 32*j];
            #pragma unroll
            for (int r = 0; r < 8; ++r)
                #pragma unroll
                for (int j = 0; j < 5; ++j)
                    acc[r][j] = fmaf(av[r], bv[j], acc[r][j]);
        }
        __syncthreads();
    }
    long base = (long)z * (128*160);
    #pragma unroll
    for (int r = 0; r < 8; ++r){
        int m = mt*8 + r;
        #pragma unroll
        for (int j = 0; j < 5; ++j)
            hpart[base + (long)m*160 + nt + 32*j] = acc[r][j];
    }
}

// ------------------------------------------------- reduce split-K partials
__global__ void k_red(const float* __restrict__ hpart, float* __restrict__ hpre){
    int t = blockIdx.x*256 + threadIdx.x;
    if (t >= 128*HID_) return;
    int b = t / HID_, n = t % HID_;
    float s = 0.0f;
    for (int z = 0; z < ZSPLIT_; ++z)
        s += hpart[(long)z*(128*160) + (long)b*160 + n];
    hpre[t] = s;
}

// ------------------------------------------------- tanh + layer2 + log_softmax
__global__ void k_final(const float* __restrict__ hpre, const float* __restrict__ b1,
        const float* __restrict__ W2, const float* __restrict__ b2,
        float* __restrict__ out){
    int b = threadIdx.x;
    if (b >= 128) return;
    float z0 = b2[0], z1 = b2[1];
    for (int n = 0; n < HID_; ++n){
        float hv = fast_tanh(hpre[(long)b*HID_ + n] + b1[n]);
        z0 = fmaf(hv, W2[n*2+0], z0);
        z1 = fmaf(hv, W2[n*2+1], z1);
    }
    float m = fmaxf(z0, z1);
    float lse = m + logf(expf(z0-m) + expf(z1-m));
    out[b*2+0] = z0 - lse;
    out[b*2+1] = z1 - lse;
}

extern "C" void kernel_launch(void* const* d_in, const int* in_sizes, int n_in,
                              void* d_out, int out_size, void* d_ws, size_t ws_size,
                              hipStream_t stream){
    const int*   sa  = (const int*)d_in[0];
    const int*   sb  = (const int*)d_in[1];
    const float* emb = (const float*)d_in[2];
    const float* hw1 = (const float*)d_in[3];
    const float* hb1 = (const float*)d_in[4];
    const float* pw1 = (const float*)d_in[5];
    const float* pb1 = (const float*)d_in[6];
    const float* hw2 = (const float*)d_in[7];
    const float* hb2 = (const float*)d_in[8];
    const float* pw2 = (const float*)d_in[9];
    const float* pb2 = (const float*)d_in[10];
    const float* hw3 = (const float*)d_in[11];
    const float* hb3 = (const float*)d_in[12];
    const float* pw3 = (const float*)d_in[13];
    const float* pb3 = (const float*)d_in[14];
    const float* W1  = (const float*)d_in[15];
    const float* b1  = (const float*)d_in[16];
    const float* W2  = (const float*)d_in[17];
    const float* b2  = (const float*)d_in[18];
    float* out = (float*)d_out;

    float* ws    = (float*)d_ws;
    float* S     = ws;                       // 300*16384      = 4,915,200
    float* APOOL = S + 4915200;              // 2*3*3*128*300  =   691,200
    float* AINF  = APOOL + 691200;           // 2*3*128        =       768
    float* PPOOL = AINF + 768;               // 2*3*2*128*6000 = 9,216,000
    float* FEAT  = PPOOL + 9216000;          // 128*44427      = 5,686,656
    float* HPRE  = FEAT + 5686656;           // 128*150        =    19,200
    // time-multiplexed overlays:
    //  - SbfT (16448*320 bf16 = 2,631,680 floats) + Wbf overlay PPOOL until hconv3
    //    finishes (k_pdim then overwrites)
    //  - HPART (512*128*160 = 10,485,760 floats) overlays S..PPOOL (dead by mlp1)
    unsigned short* SBFT = (unsigned short*)PPOOL;
    unsigned short* WBF  = (unsigned short*)(PPOOL + 2631680);
    float* HPART = ws;

    k_embed<<<64, 256, 0, stream>>>(sa, sb, emb, S);
    k_embedT<<<257, 256, 0, stream>>>(sa, sb, emb, SBFT);
    k_wprep<<<2400, 256, 0, stream>>>(hw1, hw2, hw3, WBF);
    k_hconv3<1><<<dim3(256,2), 256, 0, stream>>>(SBFT, WBF,               hb1, APOOL);
    k_hconv3<2><<<dim3(256,2), 256, 0, stream>>>(SBFT, WBF + 1*CP_*CP_,   hb2, APOOL);
    k_hconv3<3><<<dim3(256,2), 256, 0, stream>>>(SBFT, WBF + 3*CP_*CP_,   hb3, APOOL);
    k_pdim<<<6000, 256, 0, stream>>>(S, pw1,pb1, pw2,pb2, pw3,pb3, PPOOL);
    k_inf<<<256, 256, 0, stream>>>(S, AINF);
    k_pairs<<<dim3(128,3,9), 64, 0, stream>>>(APOOL, FEAT);
    k_infeat<<<1, 384, 0, stream>>>(AINF, FEAT);
    k_pdimfeat<<<dim3(128,6,20), 64, 0, stream>>>(PPOOL, FEAT);
    k_mlp1<<<dim3(ZSPLIT_), 512, 0, stream>>>(FEAT, W1, HPART);
    k_red<<<75, 256, 0, stream>>>(HPART, HPRE);
    k_final<<<1, 128, 0, stream>>>(HPRE, b1, W2, b2, out);
}

// Round 9
// 447.272 us; speedup vs baseline: 1.2628x; 1.2628x over previous
//
#include <hip/hip_runtime.h>
#include <math.h>

#define B_    128
#define L_    64
#define C_    300
#define NH_   300
#define K_    20
#define HID_  150
#define N_    (B_*L_)       // 8192
#define N2_   (2*N_)        // 16384
#define NFEAT_ 44427
#define ZSPLIT_ 512
#define KCHUNK_ 87          // 512*87 = 44544 >= 44427
#define CP_   320           // padded C for bf16 GEMM (mult of 32)
#define NROWS_ 16448        // 257*64: N2_ + pad rows (staging window reads up to +79)

typedef __attribute__((ext_vector_type(8))) short bf16x8;
typedef __attribute__((ext_vector_type(4))) float f32x4;

__device__ __forceinline__ float fast_tanh(float x){
    float e = __expf(2.0f*x);
    return 1.0f - 2.0f/(e + 1.0f);
}

__device__ __forceinline__ unsigned short f2bf(float x){
    union { float f; unsigned u; } a; a.f = x;
    unsigned r = a.u + 0x7FFFu + ((a.u >> 16) & 1u);   // RNE
    return (unsigned short)(r >> 16);
}

// async global->LDS DMA, 16B/lane; lds dest must be wave-uniform base (+lane*16)
__device__ __forceinline__ void gld16(const void* g, void* l){
    __builtin_amdgcn_global_load_lds(
        (__attribute__((address_space(1))) void*)(g),
        (__attribute__((address_space(3))) void*)(l),
        16, 0, 0);
}

// ---------------------------------------------------------------- embedding
// S[c, s*N + b*64 + l] = emb[tok(s,b,l), c]   (fp32, for pdim/inf kernels)
__global__ void k_embed(const int* __restrict__ sa, const int* __restrict__ sb,
                        const float* __restrict__ emb, float* __restrict__ S){
    int n = blockIdx.x*256 + threadIdx.x;      // 0..16383
    int s = n >> 13;
    int nl = n & (N_-1);
    int tok = s ? sb[nl] : sa[nl];
    const float* row = emb + (long)tok * C_;
    for (int c = 0; c < C_; ++c)
        S[(long)c*N2_ + n] = row[c];
}

// ------------------------------------------------- transposed bf16 S: SbfT[n][c]
__global__ void k_embedT(const int* __restrict__ sa, const int* __restrict__ sb,
                         const float* __restrict__ emb, unsigned short* __restrict__ sbfT){
    int w = threadIdx.x >> 6, lane = threadIdx.x & 63;
    for (int i = 0; i < 16; ++i){
        long n = (long)blockIdx.x*64 + w*16 + i;
        if (n >= NROWS_) return;
        bool pad = (n >= N2_);
        int tok = 0;
        if (!pad) tok = (n >= N_) ? sb[n - N_] : sa[n];
        const float4* er = (const float4*)(emb + (long)tok * C_);
        #pragma unroll
        for (int p = 0; p < 2; ++p){
            int c4 = p*64 + lane;            // float4 index, c = 4*c4
            if (c4 >= CP_/4) continue;
            ushort4 v = {0,0,0,0};
            if (!pad && c4 < 75){
                float4 f = er[c4];
                v.x = f2bf(f.x); v.y = f2bf(f.y); v.z = f2bf(f.z); v.w = f2bf(f.w);
            }
            ((ushort4*)(sbfT + n*CP_))[c4] = v;
        }
    }
}

// ------------------------------------------------- bf16 conv weights, [plane][o][c]
__global__ void k_wprep(const float* __restrict__ hw1, const float* __restrict__ hw2,
                        const float* __restrict__ hw3, unsigned short* __restrict__ wbf){
    int idx = blockIdx.x*256 + threadIdx.x;    // < 6*320*320 = 614400
    int p = idx / (CP_*CP_), r = idx % (CP_*CP_);
    int o = r / CP_, c = r % CP_;
    int WS, j; const float* hw;
    if (p == 0){ WS = 1; j = 0; hw = hw1; }
    else if (p < 3){ WS = 2; j = p - 1; hw = hw2; }
    else { WS = 3; j = p - 3; hw = hw3; }
    float v = (o < NH_ && c < C_) ? hw[((long)o*C_ + c)*WS + j] : 0.0f;
    wbf[idx] = f2bf(v);
}

// ------------------------------------------------- holistic conv via MFMA, async LDS
// Per kc chunk: waves issue global_load_lds (no VGPR round-trip: cannot sink, cannot
// spill). Double LDS buffer; the single per-iteration barrier's vmcnt(0) drain lands
// one full compute phase after issue -> chunk k+1 loads overlap chunk k MFMAs.
// LDS 16B entries: A[qc*80+row], B[(j*4+qc)*160+o] (lane-order contiguous per instr).
template<int WS>
__global__ __launch_bounds__(256) void k_hconv4(const unsigned short* __restrict__ sbfT,
        const unsigned short* __restrict__ wbf, const float* __restrict__ hb,
        float* __restrict__ apool){
    const int Lo = 65 - WS;
    const int NW = 5 + 10*WS;                  // wave-instrs per chunk (A:5, B:10*WS)
    __shared__ __align__(16) unsigned short ALB[2][320*8];      // 5120 B per buf
    __shared__ __align__(16) unsigned short BLB[2][640*WS*8];   // 10240*WS B per buf
    __shared__ float P[5][160][3];
    int tid = threadIdx.x;
    int w = tid >> 6, lane = tid & 63, col = lane & 15, quad = lane >> 4;
    int sbx = blockIdx.x, nhalf = blockIdx.y;
    int s = sbx >> 7, b = sbx & 127;
    long row0 = (long)sbx*64;
    int mt0 = (w>>1)*2;
    int olocb = (w&1)*80 + col;
    int nbase = nhalf*160;
    f32x4 acc[2][5] = {};

    auto stage = [&](int kc, int bi){
        int kbase = kc*32;
        #pragma unroll
        for (int q = 0; q < NW; ++q){
            if ((q & 3) != w) continue;        // wave-uniform branch
            int e = q*64 + lane;
            if (q < 5){
                int qc = e/80, rr = e - qc*80;
                gld16(sbfT + (row0+rr)*CP_ + kbase + qc*8, &ALB[bi][q*64*8]);
            } else {
                int eb = e - 320;
                int j = eb/640, r2 = eb - j*640;
                int qc = r2/160, o = r2 - qc*160;
                gld16(wbf + (long)j*(CP_*CP_) + (long)(nbase+o)*CP_ + kbase + qc*8,
                      &BLB[bi][(q-5)*64*8]);
            }
        }
    };

    stage(0, 0);
    for (int kc = 0; kc < 10; ++kc){
        int cur = kc & 1;
        __syncthreads();                       // drains chunk kc's loads; prior reads done
        if (kc < 9) stage(kc+1, cur^1);
        #pragma unroll
        for (int j = 0; j < WS; ++j){
            bf16x8 a0 = *(const bf16x8*)&ALB[cur][(quad*80 + mt0*16 + col + j)*8];
            bf16x8 a1 = *(const bf16x8*)&ALB[cur][(quad*80 + (mt0+1)*16 + col + j)*8];
            #pragma unroll
            for (int ni = 0; ni < 5; ++ni){
                bf16x8 bfr = *(const bf16x8*)&BLB[cur][((j*4+quad)*160 + olocb + ni*16)*8];
                acc[0][ni] = __builtin_amdgcn_mfma_f32_16x16x32_bf16(a0, bfr, acc[0][ni], 0,0,0);
                acc[1][ni] = __builtin_amdgcn_mfma_f32_16x16x32_bf16(a1, bfr, acc[1][ni], 0,0,0);
            }
        }
    }

    float rmax[5], rmin[5], rsum[5];
    #pragma unroll
    for (int ni = 0; ni < 5; ++ni){
        int oloc = olocb + ni*16;
        int o = nbase + oloc;
        float bias = (o < NH_) ? hb[o] : 0.0f;
        float vmax = -1e30f, vmin = 1e30f, vsum = 0.0f;
        #pragma unroll
        for (int mi = 0; mi < 2; ++mi){
            int mt = mt0 + mi;
            #pragma unroll
            for (int r = 0; r < 4; ++r){
                int t = mt*16 + quad*4 + r;
                if (t < Lo){
                    float z = acc[mi][ni][r] + bias;
                    vmax = fmaxf(vmax, z); vmin = fminf(vmin, z);
                    vsum += fast_tanh(z);
                }
            }
        }
        for (int m = 16; m < 64; m <<= 1){
            vmax = fmaxf(vmax, __shfl_xor(vmax, m, 64));
            vmin = fminf(vmin, __shfl_xor(vmin, m, 64));
            vsum += __shfl_xor(vsum, m, 64);
        }
        rmax[ni] = vmax; rmin[ni] = vmin; rsum[ni] = vsum;
        if (w < 2 && quad == 0){
            P[ni][oloc][0] = vmax; P[ni][oloc][1] = vmin; P[ni][oloc][2] = vsum;
        }
    }
    __syncthreads();
    if (w >= 2 && quad == 0){
        #pragma unroll
        for (int ni = 0; ni < 5; ++ni){
            int oloc = olocb + ni*16;
            int o = nbase + oloc;
            if (o < NH_){
                float vmax = fmaxf(rmax[ni], P[ni][oloc][0]);
                float vmin = fminf(rmin[ni], P[ni][oloc][1]);
                float vsum = rsum[ni] + P[ni][oloc][2];
                long base = ((long)((s*3 + (WS-1))*3)) * (long)(B_*NH_) + (long)b*NH_ + o;
                apool[base]                  = fast_tanh(vmax);
                apool[base + (long)(B_*NH_)] = -fast_tanh(vmin);
                apool[base + 2L*(B_*NH_)]    = vsum / (float)Lo;
            }
        }
    }
}

// ------------------------------------------------- per-dim conv + pooling v2
__global__ __launch_bounds__(256) void k_pdim(const float* __restrict__ S,
    const float* __restrict__ pw1, const float* __restrict__ pb1,
    const float* __restrict__ pw2, const float* __restrict__ pb2,
    const float* __restrict__ pw3, const float* __restrict__ pb3,
    float* __restrict__ ppool){
    long tid = (long)blockIdx.x*256 + threadIdx.x;   // < 1,536,000
    int k = (int)(tid % 20);
    long r = tid / 20;
    int c = (int)(r % 300); r /= 300;
    int b = (int)(r % 128); int s = (int)(r / 128);
    const float* row = S + (long)c*N2_ + (long)s*N_ + b*64;
    int ck = c*20 + k;
    float w10 = pw1[ck];
    float w20 = pw2[ck*2], w21 = pw2[ck*2+1];
    float w30 = pw3[ck*3], w31 = pw3[ck*3+1], w32 = pw3[ck*3+2];
    float bb1 = pb1[ck], bb2 = pb2[ck], bb3 = pb3[ck];

    float x[64];
    const float4* rp = (const float4*)row;
    #pragma unroll
    for (int i = 0; i < 16; ++i){
        float4 v = rp[i];
        x[i*4+0]=v.x; x[i*4+1]=v.y; x[i*4+2]=v.z; x[i*4+3]=v.w;
    }

    float mx1=-1e30f, mn1=1e30f, mx2=-1e30f, mn2=1e30f, mx3=-1e30f, mn3=1e30f;
    #pragma unroll
    for (int t = 0; t < 64; ++t){
        float z1 = fmaf(w10, x[t], bb1);
        mx1 = fmaxf(mx1, z1); mn1 = fminf(mn1, z1);
    }
    #pragma unroll
    for (int t = 0; t < 63; ++t){
        float z2 = fmaf(w21, x[t+1], fmaf(w20, x[t], bb2));
        mx2 = fmaxf(mx2, z2); mn2 = fminf(mn2, z2);
    }
    #pragma unroll
    for (int t = 0; t < 62; ++t){
        float z3 = fmaf(w32, x[t+2], fmaf(w31, x[t+1], fmaf(w30, x[t], bb3)));
        mx3 = fmaxf(mx3, z3); mn3 = fminf(mn3, z3);
    }

    float outs[6] = { fast_tanh(mx1), -fast_tanh(mn1),
                      fast_tanh(mx2), -fast_tanh(mn2),
                      fast_tanh(mx3), -fast_tanh(mn3) };
    long stride_sw = 128L*6000L;
    long off = (long)b*6000 + (long)c*20 + k;
    #pragma unroll
    for (int wsi = 0; wsi < 3; ++wsi)
        #pragma unroll
        for (int pool = 0; pool < 2; ++pool){
            long slot = (long)((s*3+wsi)*2 + pool);
            ppool[slot*stride_sw + off] = outs[wsi*2+pool];
        }
}

// ------------------------------------------------- whole-sentence (inf) pools
__global__ void k_inf(const float* __restrict__ S, float* __restrict__ ainf){
    int sbx = blockIdx.x; int s = sbx >> 7, b = sbx & 127;
    int tid = threadIdx.x;
    long base = (long)s*N_ + b*64;
    float vmax = -1e30f, vnmax = -1e30f, vsum = 0.f;
    for (int idx = tid; idx < C_*64; idx += 256){
        int c = idx >> 6, l = idx & 63;
        float v = S[(long)c*N2_ + base + l];
        vmax = fmaxf(vmax, v);
        vnmax = fmaxf(vnmax, -v);
        vsum += v;
    }
    for (int m = 1; m < 64; m <<= 1){
        vmax  = fmaxf(vmax,  __shfl_xor(vmax, m, 64));
        vnmax = fmaxf(vnmax, __shfl_xor(vnmax, m, 64));
        vsum += __shfl_xor(vsum, m, 64);
    }
    __shared__ float red[3][4];
    int w = tid >> 6;
    if ((tid & 63) == 0){ red[0][w]=vmax; red[1][w]=vnmax; red[2][w]=vsum; }
    __syncthreads();
    if (tid == 0){
        float a = fmaxf(fmaxf(red[0][0],red[0][1]),fmaxf(red[0][2],red[0][3]));
        float nn= fmaxf(fmaxf(red[1][0],red[1][1]),fmaxf(red[1][2],red[1][3]));
        float su= red[2][0]+red[2][1]+red[2][2]+red[2][3];
        ainf[(s*3+0)*128 + b] = a;
        ainf[(s*3+1)*128 + b] = nn;
        ainf[(s*3+2)*128 + b] = su / (float)(C_*64);
    }
}

// ------------------------------------------------- finite-ws pair features
__global__ void k_pairs(const float* __restrict__ apool, float* __restrict__ feat){
    int b = blockIdx.x, p = blockIdx.y, q = blockIdx.z;
    int w1 = q / 3, w2 = q % 3;
    int lane = threadIdx.x;
    const float* x1 = apool + ((long)((0*3 + w1)*3 + p))*(long)(B_*NH_) + (long)b*NH_;
    const float* x2 = apool + ((long)((1*3 + w2)*3 + p))*(long)(B_*NH_) + (long)b*NH_;
    float dot=0, n1=0, n2=0, d2=0;
    long fb = (long)b*NFEAT_;
    long vbase = 24 + (long)p*2721 + (long)q*302;
    for (int i = lane; i < NH_; i += 64){
        float a = x1[i], bb = x2[i];
        dot = fmaf(a, bb, dot); n1 = fmaf(a, a, n1); n2 = fmaf(bb, bb, n2);
        float dd = a - bb + 1e-6f;
        d2 = fmaf(dd, dd, d2);
        feat[fb + vbase + 2 + i] = fabsf(a - bb);
    }
    for (int m = 1; m < 64; m <<= 1){
        dot += __shfl_xor(dot, m, 64);
        n1  += __shfl_xor(n1, m, 64);
        n2  += __shfl_xor(n2, m, 64);
        d2  += __shfl_xor(d2, m, 64);
    }
    if (lane == 0){
        float cosv = dot / fmaxf(sqrtf(n1)*sqrtf(n2), 1e-8f);
        float distv = sqrtf(d2);
        feat[fb + vbase + 0] = cosv;
        feat[fb + vbase + 1] = distv;
        if (w1 == w2){
            feat[fb + p*8 + w1*2 + 0] = cosv;
            feat[fb + p*8 + w1*2 + 1] = distv;
        }
    }
}

// ------------------------------------------------- inf features (scalar dims)
__global__ void k_infeat(const float* __restrict__ ainf, float* __restrict__ feat){
    int t = threadIdx.x;
    if (t >= 384) return;
    int b = t & 127, p = t >> 7;
    float x1 = ainf[(0*3+p)*128 + b];
    float x2 = ainf[(1*3+p)*128 + b];
    float cosv = (x1*x2) / fmaxf(fabsf(x1)*fabsf(x2), 1e-8f);
    float distv = fabsf(x1 - x2 + 1e-6f);
    long fb = (long)b*NFEAT_;
    feat[fb + p*8 + 6] = cosv;
    feat[fb + p*8 + 7] = distv;
    long vb = 24 + (long)p*2721 + 9L*302;
    feat[fb + vb + 0] = cosv;
    feat[fb + vb + 1] = distv;
    feat[fb + vb + 2] = fabsf(x1 - x2);
}

// ------------------------------------------------- per-dim pair features
__global__ void k_pdimfeat(const float* __restrict__ ppool, float* __restrict__ feat){
    int b = blockIdx.x, pw = blockIdx.y, k = blockIdx.z;
    int pool = pw / 3, wsi = pw % 3;
    int lane = threadIdx.x;
    long stride_sw = 128L*6000L;
    long off = (long)b*6000 + k;
    const float* x1 = ppool + (long)((0*3+wsi)*2+pool)*stride_sw + off;
    const float* x2 = ppool + (long)((1*3+wsi)*2+pool)*stride_sw + off;
    float dot=0, n1=0, n2=0, d2=0;
    long fb = (long)b*NFEAT_ + 8187 + (long)pw*6040 + (long)k*302;
    for (int c = lane; c < C_; c += 64){
        float a = x1[(long)c*20], bb = x2[(long)c*20];
        dot = fmaf(a, bb, dot); n1 = fmaf(a, a, n1); n2 = fmaf(bb, bb, n2);
        float dd = a - bb + 1e-6f;
        d2 = fmaf(dd, dd, d2);
        feat[fb + 2 + c] = fabsf(a - bb);
    }
    for (int m = 1; m < 64; m <<= 1){
        dot += __shfl_xor(dot, m, 64);
        n1  += __shfl_xor(n1, m, 64);
        n2  += __shfl_xor(n2, m, 64);
        d2  += __shfl_xor(d2, m, 64);
    }
    if (lane == 0){
        feat[fb + 0] = dot / fmaxf(sqrtf(n1)*sqrtf(n2), 1e-8f);
        feat[fb + 1] = sqrtf(d2);
    }
}

// ------------------------------------------------- MLP layer 1: split-K GEMM v4
__global__ __launch_bounds__(512) void k_mlp1(const float* __restrict__ feat,
        const float* __restrict__ W1, float* __restrict__ hpart){
    __shared__ __align__(16) float AlT[32][132];   // [kx][m], reads broadcast
    __shared__ __align__(16) float Bl[32][164];    // [kx][n], pad 160->164
    int tid = threadIdx.x;
    int mt = tid >> 5;            // 0..15 -> m-base mt*8
    int nt = tid & 31;            // n = nt + 32*j
    int z  = blockIdx.x;
    int k0 = z * KCHUNK_;
    int kend = min(k0 + KCHUNK_, NFEAT_);
    float acc[8][5] = {};
    for (int kk = k0; kk < kend; kk += 32){
        {
            int kx = tid & 31, mb = tid >> 5;     // mb 0..15
            int kg = kk + kx;
            #pragma unroll
            for (int i = 0; i < 8; ++i){
                int m = mb + i*16;
                AlT[kx][m] = (kg < kend) ? feat[(long)m*NFEAT_ + kg] : 0.0f;
            }
        }
        #pragma unroll
        for (int i = 0; i < 10; ++i){
            int idx = tid + i*512;        // 0..5119
            int j = idx % 160, r = idx / 160;
            int kg = kk + r;
            Bl[r][j] = (kg < kend && j < HID_) ? W1[(long)kg*HID_ + j] : 0.0f;
        }
        __syncthreads();
        #pragma unroll 4
        for (int kx = 0; kx < 32; ++kx){
            float4 a0 = *(const float4*)&AlT[kx][mt*8];
            float4 a1 = *(const float4*)&AlT[kx][mt*8+4];
            float av[8] = {a0.x,a0.y,a0.z,a0.w, a1.x,a1.y,a1.z,a1.w};
            float bv[5];
            #pragma unroll
            for (int j = 0; j < 5; ++j) bv[j] = Bl[kx][nt + 32*j];
            #pragma unroll
            for (int r = 0; r < 8; ++r)
                #pragma unroll
                for (int j = 0; j < 5; ++j)
                    acc[r][j] = fmaf(av[r], bv[j], acc[r][j]);
        }
        __syncthreads();
    }
    long base = (long)z * (128*160);
    #pragma unroll
    for (int r = 0; r < 8; ++r){
        int m = mt*8 + r;
        #pragma unroll
        for (int j = 0; j < 5; ++j)
            hpart[base + (long)m*160 + nt + 32*j] = acc[r][j];
    }
}

// ------------------------------------------------- reduce split-K partials
__global__ void k_red(const float* __restrict__ hpart, float* __restrict__ hpre){
    int t = blockIdx.x*256 + threadIdx.x;
    if (t >= 128*HID_) return;
    int b = t / HID_, n = t % HID_;
    float s = 0.0f;
    for (int z = 0; z < ZSPLIT_; ++z)
        s += hpart[(long)z*(128*160) + (long)b*160 + n];
    hpre[t] = s;
}

// ------------------------------------------------- tanh + layer2 + log_softmax
__global__ void k_final(const float* __restrict__ hpre, const float* __restrict__ b1,
        const float* __restrict__ W2, const float* __restrict__ b2,
        float* __restrict__ out){
    int b = threadIdx.x;
    if (b >= 128) return;
    float z0 = b2[0], z1 = b2[1];
    for (int n = 0; n < HID_; ++n){
        float hv = fast_tanh(hpre[(long)b*HID_ + n] + b1[n]);
        z0 = fmaf(hv, W2[n*2+0], z0);
        z1 = fmaf(hv, W2[n*2+1], z1);
    }
    float m = fmaxf(z0, z1);
    float lse = m + logf(expf(z0-m) + expf(z1-m));
    out[b*2+0] = z0 - lse;
    out[b*2+1] = z1 - lse;
}

extern "C" void kernel_launch(void* const* d_in, const int* in_sizes, int n_in,
                              void* d_out, int out_size, void* d_ws, size_t ws_size,
                              hipStream_t stream){
    const int*   sa  = (const int*)d_in[0];
    const int*   sb  = (const int*)d_in[1];
    const float* emb = (const float*)d_in[2];
    const float* hw1 = (const float*)d_in[3];
    const float* hb1 = (const float*)d_in[4];
    const float* pw1 = (const float*)d_in[5];
    const float* pb1 = (const float*)d_in[6];
    const float* hw2 = (const float*)d_in[7];
    const float* hb2 = (const float*)d_in[8];
    const float* pw2 = (const float*)d_in[9];
    const float* pb2 = (const float*)d_in[10];
    const float* hw3 = (const float*)d_in[11];
    const float* hb3 = (const float*)d_in[12];
    const float* pw3 = (const float*)d_in[13];
    const float* pb3 = (const float*)d_in[14];
    const float* W1  = (const float*)d_in[15];
    const float* b1  = (const float*)d_in[16];
    const float* W2  = (const float*)d_in[17];
    const float* b2  = (const float*)d_in[18];
    float* out = (float*)d_out;

    float* ws    = (float*)d_ws;
    float* S     = ws;                       // 300*16384      = 4,915,200
    float* APOOL = S + 4915200;              // 2*3*3*128*300  =   691,200
    float* AINF  = APOOL + 691200;           // 2*3*128        =       768
    float* PPOOL = AINF + 768;               // 2*3*2*128*6000 = 9,216,000
    float* FEAT  = PPOOL + 9216000;          // 128*44427      = 5,686,656
    float* HPRE  = FEAT + 5686656;           // 128*150        =    19,200
    // time-multiplexed overlays:
    //  - SbfT (16448*320 bf16 = 2,631,680 floats) + Wbf overlay PPOOL until hconv4
    //    finishes (k_pdim then overwrites)
    //  - HPART (512*128*160 = 10,485,760 floats) overlays S..PPOOL (dead by mlp1)
    unsigned short* SBFT = (unsigned short*)PPOOL;
    unsigned short* WBF  = (unsigned short*)(PPOOL + 2631680);
    float* HPART = ws;

    k_embed<<<64, 256, 0, stream>>>(sa, sb, emb, S);
    k_embedT<<<257, 256, 0, stream>>>(sa, sb, emb, SBFT);
    k_wprep<<<2400, 256, 0, stream>>>(hw1, hw2, hw3, WBF);
    k_hconv4<1><<<dim3(256,2), 256, 0, stream>>>(SBFT, WBF,               hb1, APOOL);
    k_hconv4<2><<<dim3(256,2), 256, 0, stream>>>(SBFT, WBF + 1*CP_*CP_,   hb2, APOOL);
    k_hconv4<3><<<dim3(256,2), 256, 0, stream>>>(SBFT, WBF + 3*CP_*CP_,   hb3, APOOL);
    k_pdim<<<6000, 256, 0, stream>>>(S, pw1,pb1, pw2,pb2, pw3,pb3, PPOOL);
    k_inf<<<256, 256, 0, stream>>>(S, AINF);
    k_pairs<<<dim3(128,3,9), 64, 0, stream>>>(APOOL, FEAT);
    k_infeat<<<1, 384, 0, stream>>>(AINF, FEAT);
    k_pdimfeat<<<dim3(128,6,20), 64, 0, stream>>>(PPOOL, FEAT);
    k_mlp1<<<dim3(ZSPLIT_), 512, 0, stream>>>(FEAT, W1, HPART);
    k_red<<<75, 256, 0, stream>>>(HPART, HPRE);
    k_final<<<1, 128, 0, stream>>>(HPRE, b1, W2, b2, out);
}